// Round 20
// baseline (128.622 us; speedup 1.0000x reference)
//
#include <hip/hip_runtime.h>
#include <hip/hip_bf16.h>
#include <stdint.h>

#define Bb 2
#define Ss 2048
#define Ee 1024
#define Hh 16
#define Dh 64

typedef __bf16 bf16_t;
typedef __attribute__((ext_vector_type(8))) __bf16 bf16x8;
typedef __attribute__((ext_vector_type(4))) __bf16 bf16x4;
typedef __attribute__((ext_vector_type(4))) float f32x4;

// scale (1/sqrt(64)) * log2(e): scores come out in log2-domain -> exp2 direct
#define QSCALE_LOG2E 0.18033688011112042f

__device__ inline void gload_lds16(const void* g, void* l) {
  __builtin_amdgcn_global_load_lds((__attribute__((address_space(1))) void*)g,
                                   (__attribute__((address_space(3))) void*)l,
                                   16, 0, 0);
}

// Raw workgroup barrier (no implicit vmcnt(0) drain); counted vmcnt before it
// keeps the prefetch queue alive across the barrier (T4).
__device__ inline void wg_barrier() {
  asm volatile("s_barrier" ::: "memory");
}

// P-tile layout [q=16][kv=128] bf16: XOR the 16B slot index with the row.
__device__ __forceinline__ int p_addr(int q, int kv) {
  return q * 256 + ((((kv >> 3) ^ q) & 15) << 4) + (kv & 7) * 2;
}

// ---------- fp32 -> bf16 bulk convert (4 weight matrices only) ----------
struct Cvt4 {
  const float* s[4];
  bf16_t* d[4];
  int n8[4];
};

__global__ __launch_bounds__(256) void cvt_f32_bf16(Cvt4 c) {
  int gid = blockIdx.x * 256 + threadIdx.x;
#pragma unroll
  for (int j = 0; j < 4; ++j) {
    if (gid < c.n8[j]) {
      const float* s = c.s[j] + (size_t)gid * 8;
      const f32x4 lo = *(const f32x4*)s;
      const f32x4 hi = *(const f32x4*)(s + 4);
      bf16x8 v;
      v[0] = (bf16_t)lo[0]; v[1] = (bf16_t)lo[1];
      v[2] = (bf16_t)lo[2]; v[3] = (bf16_t)lo[3];
      v[4] = (bf16_t)hi[0]; v[5] = (bf16_t)hi[1];
      v[6] = (bf16_t)hi[2]; v[7] = (bf16_t)hi[3];
      *(bf16x8*)(c.d[j] + (size_t)gid * 8) = v;
      return;
    }
    gid -= c.n8[j];
  }
}

// ---------- bf16 tile staging via global_load_lds (pre-swizzled source) ----
template <int ROWS>
__device__ __forceinline__ void stage_bf16(const bf16_t* __restrict__ src,
                                           int ldk, int k0, bf16_t* lds,
                                           int wave, int lane) {
  const int srow = lane >> 3, sslot = lane & 7;
#pragma unroll
  for (int r = 0; r < ROWS / 32; ++r) {
    const int chunk = wave + r * 4;
    const int row = chunk * 8 + srow;
    const int k16 = sslot ^ (row & 7);
    gload_lds16(src + (size_t)row * ldk + k0 + k16 * 8, lds + chunk * 512);
  }
}

// ---------- 128x64-tile GEMM body (bf16 A+W, gload_lds): out_gemm ----------
template <typename EPI>
__device__ __forceinline__ void gemm_128x64(const bf16_t* Arow,
                                            const bf16_t* Wrow, bf16_t* As,
                                            bf16_t* Bs, int wave, int lane,
                                            EPI epi) {
  const int lr = lane & 15, lg = lane >> 4;
  f32x4 acc[2][4] = {};

  stage_bf16<128>(Arow, Ee, 0, As, wave, lane);
  stage_bf16<64>(Wrow, Ee, 0, Bs, wave, lane);
  stage_bf16<128>(Arow, Ee, 64, As + 8192, wave, lane);
  stage_bf16<64>(Wrow, Ee, 64, Bs + 4096, wave, lane);

  for (int t = 0; t < 16; ++t) {
    const int cur = t & 1;
    if (t < 15)
      asm volatile("s_waitcnt vmcnt(6)" ::: "memory");
    else
      asm volatile("s_waitcnt vmcnt(0)" ::: "memory");
    wg_barrier();

    const char* a_base = (const char*)(As + cur * 8192);
    const char* b_base = (const char*)(Bs + cur * 4096);
#pragma unroll
    for (int kk = 0; kk < 2; ++kk) {
      bf16x8 af[2], bfr[4];
#pragma unroll
      for (int x = 0; x < 2; ++x) {
        const int arow = wave * 32 + x * 16 + lr;
        af[x] = *(const bf16x8*)(a_base + ((arow * 128 + kk * 64 + lg * 16) ^
                                           ((arow & 7) << 4)));
      }
#pragma unroll
      for (int ni = 0; ni < 4; ++ni) {
        const int brow = ni * 16 + lr;
        bfr[ni] = *(const bf16x8*)(b_base + ((brow * 128 + kk * 64 + lg * 16) ^
                                             ((brow & 7) << 4)));
      }
#pragma unroll
      for (int mi = 0; mi < 2; ++mi)
#pragma unroll
        for (int ni = 0; ni < 4; ++ni)
          acc[mi][ni] = __builtin_amdgcn_mfma_f32_16x16x32_bf16(
              af[mi], bfr[ni], acc[mi][ni], 0, 0, 0);
    }
    wg_barrier();
    if (t + 2 < 16) {
      stage_bf16<128>(Arow, Ee, (t + 2) * 64, As + cur * 8192, wave, lane);
      stage_bf16<64>(Wrow, Ee, (t + 2) * 64, Bs + cur * 4096, wave, lane);
    }
  }

#pragma unroll
  for (int mi = 0; mi < 2; ++mi)
#pragma unroll
    for (int i = 0; i < 4; ++i) {
      const int mloc = wave * 32 + mi * 16 + lg * 4 + i;
#pragma unroll
      for (int ni = 0; ni < 4; ++ni)
        epi(mloc, ni * 16 + lr, acc[mi][ni][i]);
    }
}

// ---------- fused Q/K/V projections: fp32 A reg-staged (fused convert) -----
// A fp32 [M,K] read directly: 8 f32x4 linear loads -> cvt -> 4 swizzled
// ds_write_b128 (rule-21 both-sides pair with the swizzled MFMA reads).
// W bf16 via gload_lds dbuf. Queue/iter = 8 A + 2 W -> vmcnt(10), depth 2.
__global__ __launch_bounds__(256) void qkv_proj(
    const float* __restrict__ Aq, const float* __restrict__ Ak,
    const float* __restrict__ Av, const bf16_t* __restrict__ Wq,
    const bf16_t* __restrict__ Wk, const bf16_t* __restrict__ Wv,
    bf16_t* __restrict__ Cq, bf16_t* __restrict__ Ck,
    bf16_t* __restrict__ Cv) {
  __shared__ bf16_t As[128 * 64];   // single buffer (written from regs)
  __shared__ bf16_t Bs[2][64 * 64]; // W dbuf
  const int z = blockIdx.z;
  const float* A = (z == 0) ? Aq : (z == 1) ? Ak : Av;
  const bf16_t* W = (z == 0) ? Wq : (z == 1) ? Wk : Wv;
  bf16_t* C = (z == 0) ? Cq : (z == 1) ? Ck : Cv;

  const int wg = blockIdx.y * 16 + blockIdx.x;  // 512 per slice
  const int virt = (wg & 7) * 64 + (wg >> 3);
  const int n0 = (virt & 15) * 64, m0 = (virt >> 4) * 128;

  const int tid = threadIdx.x;
  const int lane = tid & 63, wave = tid >> 6;
  const int lr = lane & 15, lg = lane >> 4;
  const int srow = lane >> 3, sslot = lane & 7;

  const float* Arow = A + (size_t)m0 * Ee;
  const bf16_t* Wrow = W + (size_t)n0 * Ee;

  int rowv[4], wadr[4];
#pragma unroll
  for (int r = 0; r < 4; ++r) {
    rowv[r] = (wave + r * 4) * 8 + srow;
    wadr[r] = (rowv[r] * 128 + sslot * 16) ^ ((rowv[r] & 7) << 4);
  }

  f32x4 acc[2][4] = {};
  f32x4 rA[4][2], rB[4][2];  // named reg buffers (compile-time indexed)

  auto loadA = [&](int t, f32x4(&ra)[4][2]) {
#pragma unroll
    for (int r = 0; r < 4; ++r) {
      const float* s = Arow + (size_t)rowv[r] * Ee + t * 64 + sslot * 8;
      ra[r][0] = *(const f32x4*)s;
      ra[r][1] = *(const f32x4*)(s + 4);
    }
  };
  auto writeA = [&](f32x4(&ra)[4][2]) {
#pragma unroll
    for (int r = 0; r < 4; ++r) {
      bf16x8 v;
#pragma unroll
      for (int i = 0; i < 4; ++i) {
        v[i] = (bf16_t)ra[r][0][i];
        v[4 + i] = (bf16_t)ra[r][1][i];
      }
      *(bf16x8*)((char*)As + wadr[r]) = v;
    }
  };
  auto compute = [&](const bf16_t* bsbuf) {
    const char* a_base = (const char*)As;
    const char* b_base = (const char*)bsbuf;
#pragma unroll
    for (int kk = 0; kk < 2; ++kk) {
      bf16x8 af[2], bfr[4];
#pragma unroll
      for (int x = 0; x < 2; ++x) {
        const int arow = wave * 32 + x * 16 + lr;
        af[x] = *(const bf16x8*)(a_base + ((arow * 128 + kk * 64 + lg * 16) ^
                                           ((arow & 7) << 4)));
      }
#pragma unroll
      for (int ni = 0; ni < 4; ++ni) {
        const int brow = ni * 16 + lr;
        bfr[ni] = *(const bf16x8*)(b_base + ((brow * 128 + kk * 64 + lg * 16) ^
                                             ((brow & 7) << 4)));
      }
#pragma unroll
      for (int mi = 0; mi < 2; ++mi)
#pragma unroll
        for (int ni = 0; ni < 4; ++ni)
          acc[mi][ni] = __builtin_amdgcn_mfma_f32_16x16x32_bf16(
              af[mi], bfr[ni], acc[mi][ni], 0, 0, 0);
    }
  };

  // prologue: depth-2 prefetch (queue: A0x8, W0x2, A1x8, W1x2 = 20)
  loadA(0, rA);
  stage_bf16<64>(Wrow, Ee, 0, Bs[0], wave, lane);
  loadA(1, rB);
  stage_bf16<64>(Wrow, Ee, 64, Bs[1], wave, lane);

  for (int tt = 0; tt < 8; ++tt) {
    const int t0 = 2 * tt, t1 = t0 + 1;
    // ---- even step: rA, Bs[0] ----
    if (t0 < 15)
      asm volatile("s_waitcnt vmcnt(10)" ::: "memory");  // retire A(t0),W(t0)
    else
      asm volatile("s_waitcnt vmcnt(0)" ::: "memory");
    writeA(rA);
    asm volatile("s_waitcnt lgkmcnt(0)" ::: "memory");
    wg_barrier();
    compute(Bs[0]);
    wg_barrier();
    if (t0 + 2 < 16) {
      loadA(t0 + 2, rA);
      stage_bf16<64>(Wrow, Ee, (t0 + 2) * 64, Bs[0], wave, lane);
    }
    // ---- odd step: rB, Bs[1] ----
    if (t1 < 15)
      asm volatile("s_waitcnt vmcnt(10)" ::: "memory");
    else
      asm volatile("s_waitcnt vmcnt(0)" ::: "memory");
    writeA(rB);
    asm volatile("s_waitcnt lgkmcnt(0)" ::: "memory");
    wg_barrier();
    compute(Bs[1]);
    wg_barrier();
    if (t1 + 2 < 16) {
      loadA(t1 + 2, rB);
      stage_bf16<64>(Wrow, Ee, (t1 + 2) * 64, Bs[1], wave, lane);
    }
  }

  // epilogue: scatter to [B,H,S,Dh] (z<2, Q pre-scaled) or [B,H,Dh,S] (z==2)
#pragma unroll
  for (int mi = 0; mi < 2; ++mi) {
#pragma unroll
    for (int i = 0; i < 4; ++i) {
      const int m = m0 + wave * 32 + mi * 16 + lg * 4 + i;
#pragma unroll
      for (int ni = 0; ni < 4; ++ni) {
        const int n = n0 + ni * 16 + lr;
        float v = acc[mi][ni][i];
        if (z == 0) v *= QSCALE_LOG2E;
        const int b = m >> 11, s = m & (Ss - 1);
        const int h = n >> 6, d = n & 63;
        if (z != 2)
          C[(((size_t)(b * Hh + h)) * Ss + s) * Dh + d] = (bf16_t)v;
        else
          C[(((size_t)(b * Hh + h)) * Dh + d) * Ss + s] = (bf16_t)v;
      }
    }
  }
}

// ---------- output projection: bf16 gload path ----------
__global__ __launch_bounds__(256) void out_gemm(const bf16_t* __restrict__ A,
                                                const bf16_t* __restrict__ W,
                                                const float* __restrict__ bias,
                                                float* __restrict__ C) {
  __shared__ bf16_t As[2][128 * 64];
  __shared__ bf16_t Bs[2][64 * 64];
  const int wg = blockIdx.y * 16 + blockIdx.x;
  const int virt = (wg & 7) * 64 + (wg >> 3);
  const int n0 = (virt & 15) * 64, m0 = (virt >> 4) * 128;

  const int lane = threadIdx.x & 63, wave = threadIdx.x >> 6;

  gemm_128x64(A + (size_t)m0 * Ee, W + (size_t)n0 * Ee, As[0], Bs[0], wave,
              lane, [&](int mloc, int nloc, float v) {
                const int n = n0 + nloc;
                C[(size_t)(m0 + mloc) * Ee + n] = v + bias[n];
              });
}

// ---------- causal flash attention (r14 best-measured configuration) -------
__device__ __forceinline__ void attn_stage(const bf16_t* Kh, const bf16_t* Vh,
                                           int kv0, int wave, int lane,
                                           bf16_t* KsBuf, bf16_t* VsBuf) {
#pragma unroll
  for (int r = 0; r < 4; ++r) {
    const int c = wave + r * 4;  // chunk 0..15 (1KB each)
    const int krow = c * 8 + (lane >> 3);
    const int ks = (lane & 7) ^ (krow & 7);
    gload_lds16(Kh + (size_t)(kv0 + krow) * Dh + ks * 8, KsBuf + c * 512);
    const int vrow = c * 4 + (lane >> 4);
    const int vs = (lane & 15) ^ (vrow & 7);
    gload_lds16(Vh + (size_t)vrow * Ss + kv0 + vs * 8, VsBuf + c * 512);
  }
}

template <int NI, bool MASKED>
__device__ __forceinline__ void attn_tile_compute(
    int kv0, int qw, int lane, char* pb, const char* kb, const char* vb,
    const bf16x8 aq[2], float& m_run, float& l_run, f32x4 oacc[4]) {
  const int lr = lane & 15, lg = lane >> 4;

  f32x4 sc[NI];
#pragma unroll
  for (int ni = 0; ni < NI; ++ni) {
    const int krow = ni * 16 + lr;
    const bf16x8 ak0 =
        *(const bf16x8*)(kb + ((krow * 128 + lg * 16) ^ ((krow & 7) << 4)));
    const bf16x8 ak1 = *(const bf16x8*)(kb + ((krow * 128 + 64 + lg * 16) ^
                                              ((krow & 7) << 4)));
    f32x4 z = {0.f, 0.f, 0.f, 0.f};
    z = __builtin_amdgcn_mfma_f32_16x16x32_bf16(ak0, aq[0], z, 0, 0, 0);
    z = __builtin_amdgcn_mfma_f32_16x16x32_bf16(ak1, aq[1], z, 0, 0, 0);
    sc[ni] = z;
  }

  if (MASKED) {
    const int q_rel = qw + lr - kv0;
#pragma unroll
    for (int ni = 0; ni < NI; ++ni)
#pragma unroll
      for (int i = 0; i < 4; ++i)
        if (ni * 16 + lg * 4 + i > q_rel) sc[ni][i] = -1e30f;
  }

  f32x4 vm = sc[0];
#pragma unroll
  for (int ni = 1; ni < NI; ++ni)
#pragma unroll
    for (int i = 0; i < 4; ++i) vm[i] = fmaxf(vm[i], sc[ni][i]);
  float rm = fmaxf(fmaxf(vm[0], vm[1]), fmaxf(vm[2], vm[3]));
  rm = fmaxf(rm, __shfl_xor(rm, 16));
  rm = fmaxf(rm, __shfl_xor(rm, 32));

  const float mo = m_run;
  const float mn = fmaxf(mo, rm);
  const float corr = __builtin_amdgcn_exp2f(mo - mn);  // log2-domain
  m_run = mn;

  f32x4 vs = {0.f, 0.f, 0.f, 0.f};
#pragma unroll
  for (int ni = 0; ni < NI; ++ni) {
    bf16x4 w;
#pragma unroll
    for (int i = 0; i < 4; ++i) {
      const float p = __builtin_amdgcn_exp2f(sc[ni][i] - mn);
      vs[i] += p;
      w[i] = (bf16_t)p;
    }
    *(bf16x4*)(pb + p_addr(lr, ni * 16 + lg * 4)) = w;
  }
  float rs = (vs[0] + vs[1]) + (vs[2] + vs[3]);
  rs += __shfl_xor(rs, 16);
  rs += __shfl_xor(rs, 32);
  l_run = l_run * corr + rs;

#pragma unroll
  for (int i = 0; i < 4; ++i) {
    const float ci = __shfl(corr, (lane & 48) | (lg * 4 + i));
#pragma unroll
    for (int di = 0; di < 4; ++di) oacc[di][i] *= ci;
  }

#pragma unroll
  for (int kk = 0; kk < NI / 2; ++kk) {
    const bf16x8 pa = *(const bf16x8*)(pb + p_addr(lr, kk * 32 + lg * 8));
#pragma unroll
    for (int di = 0; di < 4; ++di) {
      const int vrow = di * 16 + lr;
      const bf16x8 bv = *(const bf16x8*)(vb + ((vrow * 256 + kk * 64 +
                                                lg * 16) ^
                                               ((vrow & 7) << 4)));
      oacc[di] =
          __builtin_amdgcn_mfma_f32_16x16x32_bf16(pa, bv, oacc[di], 0, 0, 0);
    }
  }
}

__device__ __forceinline__ void flash_qtile(int qt, const bf16_t* Qh,
                                            const bf16_t* Kh, const bf16_t* Vh,
                                            bf16_t* AO_row, int wave, int lane,
                                            bf16_t* Ks, bf16_t* Vs,
                                            bf16_t* PsW) {
  const int lr = lane & 15, lg = lane >> 4;
  const int qw = qt * 64 + wave * 16;

  bf16x8 aq[2];
#pragma unroll
  for (int kd = 0; kd < 2; ++kd)
    aq[kd] = *(const bf16x8*)(Qh + (size_t)(qw + lr) * Dh + kd * 32 + lg * 8);

  f32x4 oacc[4] = {};
  float m_run = -1e30f, l_run = 0.f;
  char* pb = (char*)PsW;

  const int nt = (qt + 2) >> 1;
  attn_stage(Kh, Vh, 0, wave, lane, Ks, Vs);  // 8 VMEM ops

  for (int t = 0; t < nt; ++t) {
    const int cur = t & 1;
    if (t + 1 < nt) {
      attn_stage(Kh, Vh, (t + 1) * 128, wave, lane, Ks + (cur ^ 1) * 8192,
                 Vs + (cur ^ 1) * 8192);
      asm volatile("s_waitcnt vmcnt(8)" ::: "memory");  // only tile t retired
    } else {
      asm volatile("s_waitcnt vmcnt(0)" ::: "memory");
    }
    wg_barrier();
    const char* kb = (const char*)(Ks + cur * 8192);
    const char* vb = (const char*)(Vs + cur * 8192);
    if (t < nt - 1)
      attn_tile_compute<8, false>(t * 128, qw, lane, pb, kb, vb, aq, m_run,
                                  l_run, oacc);
    else if ((qt & 1) == 0)
      attn_tile_compute<4, true>(t * 128, qw, lane, pb, kb, vb, aq, m_run,
                                 l_run, oacc);
    else
      attn_tile_compute<8, true>(t * 128, qw, lane, pb, kb, vb, aq, m_run,
                                 l_run, oacc);
    wg_barrier();
  }

#pragma unroll
  for (int i = 0; i < 4; ++i) {
    const float li = __shfl(l_run, (lane & 48) | (lg * 4 + i));
    const float inv = 1.0f / li;
    const int s = qw + lg * 4 + i;
#pragma unroll
    for (int di = 0; di < 4; ++di) {
      const int d = di * 16 + lr;
      AO_row[(size_t)s * Ee + d] = (bf16_t)(oacc[di][i] * inv);
    }
  }
}

__global__ __launch_bounds__(256, 2) void attn_causal(
    const bf16_t* __restrict__ Qg, const bf16_t* __restrict__ Kg,
    const bf16_t* __restrict__ Vg, bf16_t* __restrict__ AO) {
  const int wg = blockIdx.y * 16 + blockIdx.x;
  const int virt = (wg & 7) * 64 + (wg >> 3);
  const int qx = virt & 15;
  const int bh = virt >> 4;

  const int tid = threadIdx.x;
  const int lane = tid & 63, wave = tid >> 6;

  const bf16_t* Qh = Qg + (size_t)bh * Ss * Dh;
  const bf16_t* Kh = Kg + (size_t)bh * Ss * Dh;
  const bf16_t* Vh = Vg + (size_t)bh * Dh * Ss;
  const int b = bh >> 4, h = bh & 15;
  bf16_t* AO_row = AO + (size_t)b * Ss * Ee + h * 64;

  __shared__ bf16_t Ks[2][128 * 64];
  __shared__ bf16_t Vs[2][64 * 128];
  __shared__ bf16_t Ps[4][16 * 128];

  const int qtA = qx;
  const int qtB = 31 - qx;
  flash_qtile(qtA, Qh, Kh, Vh, AO_row, wave, lane, Ks[0], Vs[0], Ps[wave]);
  flash_qtile(qtB, Qh, Kh, Vh, AO_row, wave, lane, Ks[0], Vs[0], Ps[wave]);
}

extern "C" void kernel_launch(void* const* d_in, const int* in_sizes, int n_in,
                              void* d_out, int out_size, void* d_ws,
                              size_t ws_size, hipStream_t stream) {
  const float* query = (const float*)d_in[0];
  const float* key = (const float*)d_in[1];
  const float* value = (const float*)d_in[2];
  // d_in[3] = causal mask (triu k=1) — structure known, not read
  const float* Wq = (const float*)d_in[4];
  const float* Wk = (const float*)d_in[5];
  const float* Wv = (const float*)d_in[6];
  const float* Wo = (const float*)d_in[7];
  const float* bo = (const float*)d_in[8];

  const size_t T = (size_t)Bb * Ss * Ee;  // 4,194,304
  const size_t WN = (size_t)Ee * Ee;      // 1,048,576
  bf16_t* wqb = (bf16_t*)d_ws;  // weight bf16 copies
  bf16_t* wkb = wqb + WN;
  bf16_t* wvb = wkb + WN;
  bf16_t* wob = wvb + WN;
  bf16_t* qws = wob + WN;  // projected Q/K/V
  bf16_t* kws = qws + T;
  bf16_t* vws = kws + T;
  bf16_t* aows = vws + T;  // attention out

  Cvt4 c;
  c.s[0] = Wq; c.d[0] = wqb; c.n8[0] = (int)(WN / 8);
  c.s[1] = Wk; c.d[1] = wkb; c.n8[1] = (int)(WN / 8);
  c.s[2] = Wv; c.d[2] = wvb; c.n8[2] = (int)(WN / 8);
  c.s[3] = Wo; c.d[3] = wob; c.n8[3] = (int)(WN / 8);
  const int total8 = (int)((4 * WN) / 8);  // 524,288

  dim3 blk(256);
  cvt_f32_bf16<<<dim3(total8 / 256), blk, 0, stream>>>(c);
  qkv_proj<<<dim3(Ee / 64, (Bb * Ss) / 128, 3), blk, 0, stream>>>(
      query, key, value, wqb, wkb, wvb, qws, kws, vws);
  attn_causal<<<dim3(16, Bb * Hh), blk, 0, stream>>>(qws, kws, vws, aows);
  out_gemm<<<dim3(Ee / 64, (Bb * Ss) / 128), blk, 0, stream>>>(
      aows, wob, bo, (float*)d_out);
}

// Round 21
// 111.880 us; speedup vs baseline: 1.1496x; 1.1496x over previous
//
#include <hip/hip_runtime.h>
#include <hip/hip_bf16.h>
#include <stdint.h>

#define Bb 2
#define Ss 2048
#define Ee 1024
#define Hh 16
#define Dh 64

typedef __bf16 bf16_t;
typedef __attribute__((ext_vector_type(8))) __bf16 bf16x8;
typedef __attribute__((ext_vector_type(4))) __bf16 bf16x4;
typedef __attribute__((ext_vector_type(4))) float f32x4;

// scale (1/sqrt(64)) * log2(e): scores come out in log2-domain -> exp2 direct
#define QSCALE_LOG2E 0.18033688011112042f

__device__ inline void gload_lds16(const void* g, void* l) {
  __builtin_amdgcn_global_load_lds((__attribute__((address_space(1))) void*)g,
                                   (__attribute__((address_space(3))) void*)l,
                                   16, 0, 0);
}

// Raw workgroup barrier (no implicit vmcnt(0) drain); counted vmcnt before it
// keeps the prefetch queue alive across the barrier (T4).
__device__ inline void wg_barrier() {
  asm volatile("s_barrier" ::: "memory");
}

// P-tile layout [q=16][kv=128] bf16: XOR the 16B slot index with the row.
// Conflict-free for both the 8B softmax stores and the 16B PV reads.
__device__ __forceinline__ int p_addr(int q, int kv) {
  return q * 256 + ((((kv >> 3) ^ q) & 15) << 4) + (kv & 7) * 2;
}

// ---------- fp32 -> bf16 bulk convert (7 buffers, one launch) ----------
struct Cvt7 {
  const float* s[7];
  bf16_t* d[7];
  int n8[7];
};

__global__ __launch_bounds__(256) void cvt_f32_bf16(Cvt7 c) {
  int gid = blockIdx.x * 256 + threadIdx.x;
#pragma unroll
  for (int j = 0; j < 7; ++j) {
    if (gid < c.n8[j]) {
      const float* s = c.s[j] + (size_t)gid * 8;
      const f32x4 lo = *(const f32x4*)s;
      const f32x4 hi = *(const f32x4*)(s + 4);
      bf16x8 v;
      v[0] = (bf16_t)lo[0]; v[1] = (bf16_t)lo[1];
      v[2] = (bf16_t)lo[2]; v[3] = (bf16_t)lo[3];
      v[4] = (bf16_t)hi[0]; v[5] = (bf16_t)hi[1];
      v[6] = (bf16_t)hi[2]; v[7] = (bf16_t)hi[3];
      *(bf16x8*)(c.d[j] + (size_t)gid * 8) = v;
      return;
    }
    gid -= c.n8[j];
  }
}

// ---------- bf16 tile staging via global_load_lds (pre-swizzled source) ----
template <int ROWS>
__device__ __forceinline__ void stage_bf16(const bf16_t* __restrict__ src,
                                           int ldk, int k0, bf16_t* lds,
                                           int wave, int lane) {
  const int srow = lane >> 3, sslot = lane & 7;
#pragma unroll
  for (int r = 0; r < ROWS / 32; ++r) {
    const int chunk = wave + r * 4;
    const int row = chunk * 8 + srow;
    const int k16 = sslot ^ (row & 7);
    gload_lds16(src + (size_t)row * ldk + k0 + k16 * 8, lds + chunk * 512);
  }
}

// ---------- 128x64-tile GEMM body: dbuf + counted vmcnt + raw barrier ------
template <typename EPI>
__device__ __forceinline__ void gemm_128x64(const bf16_t* Arow,
                                            const bf16_t* Wrow, bf16_t* As,
                                            bf16_t* Bs, int wave, int lane,
                                            EPI epi) {
  const int lr = lane & 15, lg = lane >> 4;
  f32x4 acc[2][4] = {};

  // prologue: tiles 0 and 1 (6 VMEM ops each: 4 A + 2 B)
  stage_bf16<128>(Arow, Ee, 0, As, wave, lane);
  stage_bf16<64>(Wrow, Ee, 0, Bs, wave, lane);
  stage_bf16<128>(Arow, Ee, 64, As + 8192, wave, lane);
  stage_bf16<64>(Wrow, Ee, 64, Bs + 4096, wave, lane);

  for (int t = 0; t < 16; ++t) {
    const int cur = t & 1;
    if (t < 15)
      asm volatile("s_waitcnt vmcnt(6)" ::: "memory");
    else
      asm volatile("s_waitcnt vmcnt(0)" ::: "memory");
    wg_barrier();

    const char* a_base = (const char*)(As + cur * 8192);
    const char* b_base = (const char*)(Bs + cur * 4096);
#pragma unroll
    for (int kk = 0; kk < 2; ++kk) {
      bf16x8 af[2], bfr[4];
#pragma unroll
      for (int x = 0; x < 2; ++x) {
        const int arow = wave * 32 + x * 16 + lr;
        af[x] = *(const bf16x8*)(a_base + ((arow * 128 + kk * 64 + lg * 16) ^
                                           ((arow & 7) << 4)));
      }
#pragma unroll
      for (int ni = 0; ni < 4; ++ni) {
        const int brow = ni * 16 + lr;
        bfr[ni] = *(const bf16x8*)(b_base + ((brow * 128 + kk * 64 + lg * 16) ^
                                             ((brow & 7) << 4)));
      }
#pragma unroll
      for (int mi = 0; mi < 2; ++mi)
#pragma unroll
        for (int ni = 0; ni < 4; ++ni)
          acc[mi][ni] = __builtin_amdgcn_mfma_f32_16x16x32_bf16(
              af[mi], bfr[ni], acc[mi][ni], 0, 0, 0);
    }
    wg_barrier();
    if (t + 2 < 16) {
      stage_bf16<128>(Arow, Ee, (t + 2) * 64, As + cur * 8192, wave, lane);
      stage_bf16<64>(Wrow, Ee, (t + 2) * 64, Bs + cur * 4096, wave, lane);
    }
  }

#pragma unroll
  for (int mi = 0; mi < 2; ++mi)
#pragma unroll
    for (int i = 0; i < 4; ++i) {
      const int mloc = wave * 32 + mi * 16 + lg * 4 + i;
#pragma unroll
      for (int ni = 0; ni < 4; ++ni)
        epi(mloc, ni * 16 + lr, acc[mi][ni][i]);
    }
}

// ---------- fused Q/K/V projections: 128x64 tiles, 1536 blocks, 3/CU -------
__global__ __launch_bounds__(256) void qkv_proj(
    const bf16_t* __restrict__ Aq, const bf16_t* __restrict__ Ak,
    const bf16_t* __restrict__ Av, const bf16_t* __restrict__ Wq,
    const bf16_t* __restrict__ Wk, const bf16_t* __restrict__ Wv,
    bf16_t* __restrict__ Cq, bf16_t* __restrict__ Ck,
    bf16_t* __restrict__ Cv) {
  __shared__ bf16_t As[2][128 * 64];
  __shared__ bf16_t Bs[2][64 * 64];
  const int z = blockIdx.z;
  const bf16_t* A = (z == 0) ? Aq : (z == 1) ? Ak : Av;
  const bf16_t* W = (z == 0) ? Wq : (z == 1) ? Wk : Wv;
  bf16_t* C = (z == 0) ? Cq : (z == 1) ? Ck : Cv;

  const int wg = blockIdx.y * 16 + blockIdx.x;  // 512 per slice
  const int virt = (wg & 7) * 64 + (wg >> 3);
  const int n0 = (virt & 15) * 64, m0 = (virt >> 4) * 128;

  const int lane = threadIdx.x & 63, wave = threadIdx.x >> 6;

  gemm_128x64(A + (size_t)m0 * Ee, W + (size_t)n0 * Ee, As[0], Bs[0], wave,
              lane, [&](int mloc, int nloc, float v) {
                const int m = m0 + mloc, n = n0 + nloc;
                if (z == 0) v *= QSCALE_LOG2E;  // fold scale*log2e into Q
                const int b = m >> 11, s = m & (Ss - 1);
                const int h = n >> 6, d = n & 63;
                if (z != 2)
                  C[(((size_t)(b * Hh + h)) * Ss + s) * Dh + d] = (bf16_t)v;
                else
                  C[(((size_t)(b * Hh + h)) * Dh + d) * Ss + s] = (bf16_t)v;
              });
}

// ---------- output projection: identical structure ----------
__global__ __launch_bounds__(256) void out_gemm(const bf16_t* __restrict__ A,
                                                const bf16_t* __restrict__ W,
                                                const float* __restrict__ bias,
                                                float* __restrict__ C) {
  __shared__ bf16_t As[2][128 * 64];
  __shared__ bf16_t Bs[2][64 * 64];
  const int wg = blockIdx.y * 16 + blockIdx.x;
  const int virt = (wg & 7) * 64 + (wg >> 3);
  const int n0 = (virt & 15) * 64, m0 = (virt >> 4) * 128;

  const int lane = threadIdx.x & 63, wave = threadIdx.x >> 6;

  gemm_128x64(A + (size_t)m0 * Ee, W + (size_t)n0 * Ee, As[0], Bs[0], wave,
              lane, [&](int mloc, int nloc, float v) {
                const int n = n0 + nloc;
                C[(size_t)(m0 + mloc) * Ee + n] = v + bias[n];
              });
}

// ---------- causal flash attention (r14 best-measured configuration) -------
// Q,K: [B,H,S,Dh] bf16 (Q pre-scaled by 0.125*log2e); V: [B,H,Dh,S] bf16.
// KVBLK=128, dbuf + counted vmcnt + raw barriers; paired q-tiles {x,31-x}
// give every block exactly 17 uniform iterations (no drain tail).

__device__ __forceinline__ void attn_stage(const bf16_t* Kh, const bf16_t* Vh,
                                           int kv0, int wave, int lane,
                                           bf16_t* KsBuf, bf16_t* VsBuf) {
#pragma unroll
  for (int r = 0; r < 4; ++r) {
    const int c = wave + r * 4;  // chunk 0..15 (1KB each)
    const int krow = c * 8 + (lane >> 3);
    const int ks = (lane & 7) ^ (krow & 7);
    gload_lds16(Kh + (size_t)(kv0 + krow) * Dh + ks * 8, KsBuf + c * 512);
    const int vrow = c * 4 + (lane >> 4);
    const int vs = (lane & 15) ^ (vrow & 7);
    gload_lds16(Vh + (size_t)vrow * Ss + kv0 + vs * 8, VsBuf + c * 512);
  }
}

template <int NI, bool MASKED>
__device__ __forceinline__ void attn_tile_compute(
    int kv0, int qw, int lane, char* pb, const char* kb, const char* vb,
    const bf16x8 aq[2], float& m_run, float& l_run, f32x4 oacc[4]) {
  const int lr = lane & 15, lg = lane >> 4;

  // ---- S^T = K Q^T : sc[ni][i] = S[kv0 + ni*16 + lg*4 + i][qw + lr] ----
  f32x4 sc[NI];
#pragma unroll
  for (int ni = 0; ni < NI; ++ni) {
    const int krow = ni * 16 + lr;
    const bf16x8 ak0 =
        *(const bf16x8*)(kb + ((krow * 128 + lg * 16) ^ ((krow & 7) << 4)));
    const bf16x8 ak1 = *(const bf16x8*)(kb + ((krow * 128 + 64 + lg * 16) ^
                                              ((krow & 7) << 4)));
    f32x4 z = {0.f, 0.f, 0.f, 0.f};
    z = __builtin_amdgcn_mfma_f32_16x16x32_bf16(ak0, aq[0], z, 0, 0, 0);
    z = __builtin_amdgcn_mfma_f32_16x16x32_bf16(ak1, aq[1], z, 0, 0, 0);
    sc[ni] = z;
  }

  if (MASKED) {
    const int q_rel = qw + lr - kv0;  // keep kv_local <= q_rel
#pragma unroll
    for (int ni = 0; ni < NI; ++ni)
#pragma unroll
      for (int i = 0; i < 4; ++i)
        if (ni * 16 + lg * 4 + i > q_rel) sc[ni][i] = -1e30f;
  }

  // ---- row max: in-lane tree + cross-lg ----
  f32x4 vm = sc[0];
#pragma unroll
  for (int ni = 1; ni < NI; ++ni)
#pragma unroll
    for (int i = 0; i < 4; ++i) vm[i] = fmaxf(vm[i], sc[ni][i]);
  float rm = fmaxf(fmaxf(vm[0], vm[1]), fmaxf(vm[2], vm[3]));
  rm = fmaxf(rm, __shfl_xor(rm, 16));
  rm = fmaxf(rm, __shfl_xor(rm, 32));

  const float mo = m_run;
  const float mn = fmaxf(mo, rm);
  const float corr = __builtin_amdgcn_exp2f(mo - mn);  // log2-domain
  m_run = mn;

  // ---- p = exp2(s - m); packed 4-wide P store (conflict-free layout) ----
  f32x4 vs = {0.f, 0.f, 0.f, 0.f};
#pragma unroll
  for (int ni = 0; ni < NI; ++ni) {
    bf16x4 w;
#pragma unroll
    for (int i = 0; i < 4; ++i) {
      const float p = __builtin_amdgcn_exp2f(sc[ni][i] - mn);
      vs[i] += p;
      w[i] = (bf16_t)p;
    }
    // P[q=lr][kv = ni*16 + lg*4 + 0..3]
    *(bf16x4*)(pb + p_addr(lr, ni * 16 + lg * 4)) = w;
  }
  float rs = (vs[0] + vs[1]) + (vs[2] + vs[3]);
  rs += __shfl_xor(rs, 16);
  rs += __shfl_xor(rs, 32);
  l_run = l_run * corr + rs;

  // ---- rescale O ----
#pragma unroll
  for (int i = 0; i < 4; ++i) {
    const float ci = __shfl(corr, (lane & 48) | (lg * 4 + i));
#pragma unroll
    for (int di = 0; di < 4; ++di) oacc[di][i] *= ci;
  }

  // ---- O += P V ----
#pragma unroll
  for (int kk = 0; kk < NI / 2; ++kk) {
    // P[q=lr][kv = kk*32 + lg*8 + 0..7]
    const bf16x8 pa = *(const bf16x8*)(pb + p_addr(lr, kk * 32 + lg * 8));
#pragma unroll
    for (int di = 0; di < 4; ++di) {
      const int vrow = di * 16 + lr;
      const bf16x8 bv = *(const bf16x8*)(vb + ((vrow * 256 + kk * 64 +
                                                lg * 16) ^
                                               ((vrow & 7) << 4)));
      oacc[di] =
          __builtin_amdgcn_mfma_f32_16x16x32_bf16(pa, bv, oacc[di], 0, 0, 0);
    }
  }
}

__device__ __forceinline__ void flash_qtile(int qt, const bf16_t* Qh,
                                            const bf16_t* Kh, const bf16_t* Vh,
                                            bf16_t* AO_row, int wave, int lane,
                                            bf16_t* Ks, bf16_t* Vs,
                                            bf16_t* PsW) {
  const int lr = lane & 15, lg = lane >> 4;
  const int qw = qt * 64 + wave * 16;

  bf16x8 aq[2];
#pragma unroll
  for (int kd = 0; kd < 2; ++kd)
    aq[kd] = *(const bf16x8*)(Qh + (size_t)(qw + lr) * Dh + kd * 32 + lg * 8);

  f32x4 oacc[4] = {};
  float m_run = -1e30f, l_run = 0.f;
  char* pb = (char*)PsW;

  const int nt = (qt + 2) >> 1;  // 128-wide kv tiles for causal coverage
  attn_stage(Kh, Vh, 0, wave, lane, Ks, Vs);  // 8 VMEM ops

  for (int t = 0; t < nt; ++t) {
    const int cur = t & 1;
    if (t + 1 < nt) {
      attn_stage(Kh, Vh, (t + 1) * 128, wave, lane, Ks + (cur ^ 1) * 8192,
                 Vs + (cur ^ 1) * 8192);  // +8 in flight
      asm volatile("s_waitcnt vmcnt(8)" ::: "memory");  // only tile t retired
    } else {
      asm volatile("s_waitcnt vmcnt(0)" ::: "memory");
    }
    wg_barrier();
    const char* kb = (const char*)(Ks + cur * 8192);
    const char* vb = (const char*)(Vs + cur * 8192);
    if (t < nt - 1)
      attn_tile_compute<8, false>(t * 128, qw, lane, pb, kb, vb, aq, m_run,
                                  l_run, oacc);
    else if ((qt & 1) == 0)  // even diagonal: upper 64 kv fully masked
      attn_tile_compute<4, true>(t * 128, qw, lane, pb, kb, vb, aq, m_run,
                                 l_run, oacc);
    else
      attn_tile_compute<8, true>(t * 128, qw, lane, pb, kb, vb, aq, m_run,
                                 l_run, oacc);
    wg_barrier();  // all waves done reading buf[cur] before refill
  }

#pragma unroll
  for (int i = 0; i < 4; ++i) {
    const float li = __shfl(l_run, (lane & 48) | (lg * 4 + i));
    const float inv = 1.0f / li;
    const int s = qw + lg * 4 + i;
#pragma unroll
    for (int di = 0; di < 4; ++di) {
      const int d = di * 16 + lr;
      AO_row[(size_t)s * Ee + d] = (bf16_t)(oacc[di][i] * inv);
    }
  }
}

__global__ __launch_bounds__(256, 2) void attn_causal(
    const bf16_t* __restrict__ Qg, const bf16_t* __restrict__ Kg,
    const bf16_t* __restrict__ Vg, bf16_t* __restrict__ AO) {
  // XCD swizzle: 512 blocks -> 4 heads per XCD (K/V L2-resident)
  const int wg = blockIdx.y * 16 + blockIdx.x;
  const int virt = (wg & 7) * 64 + (wg >> 3);
  const int qx = virt & 15;
  const int bh = virt >> 4;

  const int tid = threadIdx.x;
  const int lane = tid & 63, wave = tid >> 6;

  const bf16_t* Qh = Qg + (size_t)bh * Ss * Dh;
  const bf16_t* Kh = Kg + (size_t)bh * Ss * Dh;
  const bf16_t* Vh = Vg + (size_t)bh * Dh * Ss;
  const int b = bh >> 4, h = bh & 15;
  bf16_t* AO_row = AO + (size_t)b * Ss * Ee + h * 64;

  __shared__ bf16_t Ks[2][128 * 64];  // K tiles, swizzled, dbuf
  __shared__ bf16_t Vs[2][64 * 128];  // V^T tiles, swizzled, dbuf
  __shared__ bf16_t Ps[4][16 * 128];  // per-wave P, p_addr layout

  const int qtA = qx;       // short tile
  const int qtB = 31 - qx;  // long tile — uniform 17 iters per block
  flash_qtile(qtA, Qh, Kh, Vh, AO_row, wave, lane, Ks[0], Vs[0], Ps[wave]);
  flash_qtile(qtB, Qh, Kh, Vh, AO_row, wave, lane, Ks[0], Vs[0], Ps[wave]);
}

extern "C" void kernel_launch(void* const* d_in, const int* in_sizes, int n_in,
                              void* d_out, int out_size, void* d_ws,
                              size_t ws_size, hipStream_t stream) {
  const float* query = (const float*)d_in[0];
  const float* key = (const float*)d_in[1];
  const float* value = (const float*)d_in[2];
  // d_in[3] = causal mask (triu k=1) — structure known, not read
  const float* Wq = (const float*)d_in[4];
  const float* Wk = (const float*)d_in[5];
  const float* Wv = (const float*)d_in[6];
  const float* Wo = (const float*)d_in[7];
  const float* bo = (const float*)d_in[8];

  const size_t T = (size_t)Bb * Ss * Ee;  // 4,194,304
  const size_t WN = (size_t)Ee * Ee;      // 1,048,576
  bf16_t* qbf = (bf16_t*)d_ws;
  bf16_t* kbf = qbf + T;
  bf16_t* vbf = kbf + T;
  bf16_t* wqb = vbf + T;
  bf16_t* wkb = wqb + WN;
  bf16_t* wvb = wkb + WN;
  bf16_t* wob = wvb + WN;
  bf16_t* qws = wob + WN;
  bf16_t* kws = qws + T;
  bf16_t* vws = kws + T;
  bf16_t* aows = qbf;  // overlay: qbf dead after qkv_proj

  Cvt7 c;
  c.s[0] = query; c.d[0] = qbf; c.n8[0] = (int)(T / 8);
  c.s[1] = key;   c.d[1] = kbf; c.n8[1] = (int)(T / 8);
  c.s[2] = value; c.d[2] = vbf; c.n8[2] = (int)(T / 8);
  c.s[3] = Wq;    c.d[3] = wqb; c.n8[3] = (int)(WN / 8);
  c.s[4] = Wk;    c.d[4] = wkb; c.n8[4] = (int)(WN / 8);
  c.s[5] = Wv;    c.d[5] = wvb; c.n8[5] = (int)(WN / 8);
  c.s[6] = Wo;    c.d[6] = wob; c.n8[6] = (int)(WN / 8);
  const int total8 = (int)((3 * T + 4 * WN) / 8);

  dim3 blk(256);
  cvt_f32_bf16<<<dim3(total8 / 256), blk, 0, stream>>>(c);
  qkv_proj<<<dim3(Ee / 64, (Bb * Ss) / 128, 3), blk, 0, stream>>>(
      qbf, kbf, vbf, wqb, wkb, wvb, qws, kws, vws);
  attn_causal<<<dim3(16, Bb * Hh), blk, 0, stream>>>(qws, kws, vws, aows);
  out_gemm<<<dim3(Ee / 64, (Bb * Ss) / 128), blk, 0, stream>>>(
      aows, wob, bo, (float*)d_out);
}